// Round 4
// baseline (20406.593 us; speedup 1.0000x reference)
//
#include <hip/hip_runtime.h>
#include <cstddef>

#define S_LEN 32768
#define HID 32
#define NG 128          // 4*H
#define IN_DIM 2048
#define L2E 1.44269504088896340736f
#define NGRP 8194       // groups of 4 timesteps; covers t=32767 for wave 2

typedef float v2f __attribute__((ext_vector_type(2)));
typedef float v4f __attribute__((ext_vector_type(4)));

__device__ __forceinline__ v2f pkfma(v2f a, v2f b, v2f c){
  asm("v_pk_fma_f32 %0, %1, %2, %0" : "+v"(c) : "v"(a), "v"(b));
  return c;
}
__device__ __forceinline__ float fexp2(float x){ float r; asm("v_exp_f32 %0, %1" : "=v"(r) : "v"(x)); return r; }
__device__ __forceinline__ float frcp (float x){ float r; asm("v_rcp_f32 %0, %1" : "=v"(r) : "v"(x)); return r; }
__device__ __forceinline__ v2f vlo(v4f v){ v2f r; r.x = v.x; r.y = v.y; return r; }
__device__ __forceinline__ v2f vhi(v4f v){ v2f r; r.x = v.z; r.y = v.w; return r; }

// unpack u32 of two bf16 (lo = element k, hi = element k+1) to v2f
__device__ __forceinline__ v2f bf2f2(unsigned u){
  v2f r;
  r.x = __builtin_bit_cast(float, u << 16);
  r.y = __builtin_bit_cast(float, u & 0xffff0000u);
  return r;
}
// f32 -> bf16 (RNE) via HW pack (low 16 bits of result)
__device__ __forceinline__ unsigned f2bf(float x){
  unsigned r;
  asm("v_cvt_pk_bf16_f32 %0, %1, %2" : "=v"(r) : "v"(x), "v"(x));
  return r;
}
// Sum across lane pair (j, j^32), orientation-independent.
__device__ __forceinline__ float pairsum32(float v){
  float a = v, b = v;
  asm("v_permlane32_swap_b32 %0, %1" : "+v"(a), "+v"(b));
  return a + b;
}
// Raw barrier: LDS-ordering only, does NOT drain vmcnt.
__device__ __forceinline__ void wg_barrier(){
  __builtin_amdgcn_sched_barrier(0);
  asm volatile("s_waitcnt lgkmcnt(0)");
  __builtin_amdgcn_s_barrier();
  __builtin_amdgcn_sched_barrier(0);
}

// ---------------------------------------------------------------------------
// Kernel 1: pre0[t][g] = s_g * ( x[t].w_ih0[g] + b_ih0[g] + b_hh0[g] ),
// permuted pos = 4*(g&31) + (g>>5) so a scan lane reads one v4f (i,f,g,o).
// ---------------------------------------------------------------------------
__global__ __launch_bounds__(256) void pre0_kernel(
    const float* __restrict__ ctxt, const float* __restrict__ freq,
    const float* __restrict__ fert, const float* __restrict__ wf,
    const float* __restrict__ bf,   const float* __restrict__ we,
    const float* __restrict__ be,   const float* __restrict__ w_ih0,
    const float* __restrict__ b_ih0,const float* __restrict__ b_hh0,
    float* __restrict__ pre0)
{
  __shared__ float Xs[32][132];
  __shared__ float Ws[32][132];
  const int tid = threadIdx.x;
  const int t0  = blockIdx.x * 128;
  const int cx  = tid & 15;
  const int ry  = tid >> 4;
  const int kk  = tid & 31;
  const int rr  = tid >> 5;

  float acc[8][8];
  #pragma unroll
  for (int i = 0; i < 8; i++)
    #pragma unroll
    for (int c = 0; c < 8; c++) acc[i][c] = 0.f;

  for (int kc = 0; kc < IN_DIM; kc += 32){
    #pragma unroll
    for (int i = 0; i < 16; i++){
      int r = rr + 8*i;
      int K = kc + kk;
      float v;
      if (K < 1024){
        v = ctxt[(size_t)(t0 + r)*1024 + K];
      } else if (K < 1536){
        int j = K - 1024;
        float u = fmaf(freq[t0 + r], wf[j], bf[j]);
        v = fmaxf(u, 0.01f*u);
      } else {
        int j = K - 1536;
        float u = fmaf(fert[t0 + r], we[j], be[j]);
        v = fmaxf(u, 0.01f*u);
      }
      Xs[kk][r] = v;
    }
    #pragma unroll
    for (int i = 0; i < 16; i++){
      int g = rr + 8*i;
      float sc = (g >= 64 && g < 96) ? (-2.f*L2E) : (-L2E);
      Ws[kk][g] = w_ih0[(size_t)g*IN_DIM + kc + kk] * sc;
    }
    __syncthreads();
    #pragma unroll
    for (int k = 0; k < 32; k++){
      v4f xa = *(const v4f*)&Xs[k][8*ry];
      v4f xb = *(const v4f*)&Xs[k][8*ry + 4];
      v4f wa = *(const v4f*)&Ws[k][8*cx];
      v4f wb = *(const v4f*)&Ws[k][8*cx + 4];
      float xr[8] = {xa.x,xa.y,xa.z,xa.w,xb.x,xb.y,xb.z,xb.w};
      float wc[8] = {wa.x,wa.y,wa.z,wa.w,wb.x,wb.y,wb.z,wb.w};
      #pragma unroll
      for (int i = 0; i < 8; i++)
        #pragma unroll
        for (int c = 0; c < 8; c++)
          acc[i][c] = fmaf(xr[i], wc[c], acc[i][c]);
    }
    __syncthreads();
  }
  #pragma unroll
  for (int i = 0; i < 8; i++){
    int r = t0 + 8*ry + i;
    #pragma unroll
    for (int c = 0; c < 8; c++){
      int g = 8*cx + c;
      int tau = g >> 5, uu = g & 31;
      float sc = (tau == 2) ? (-2.f*L2E) : (-L2E);
      int pos = 4*uu + tau;
      pre0[(size_t)r*NG + pos] = acc[i][c] + (b_ih0[g] + b_hh0[g])*sc;
    }
  }
}

// ---------------------------------------------------------------------------
// Kernel 2: scan. 1 block, 3 waves = 3 layers, skew-4 pipeline (1 barrier per
// 4 steps). h ring in LDS as bf16 (halves DS ops: own 2 + cross 2 reads, b16
// write). Lane pair (j, j+32) k-splits all 4 gates of unit j; pairs combined
// via v_permlane32_swap_b32. Own/cross accumulators split (short dep chains).
// ---------------------------------------------------------------------------
__global__ __launch_bounds__(192, 1) void scan_kernel(
    const float* __restrict__ pre0,
    const float* __restrict__ w_hh0,
    const float* __restrict__ w_ih1, const float* __restrict__ w_hh1,
    const float* __restrict__ b_ih1, const float* __restrict__ b_hh1,
    const float* __restrict__ w_ih2, const float* __restrict__ w_hh2,
    const float* __restrict__ b_ih2, const float* __restrict__ b_hh2,
    float* __restrict__ h2out)
{
  __shared__ __align__(16) unsigned short hsb[3][8][HID];  // bf16 h ring
  const int tid  = threadIdx.x;
  const int wv   = tid >> 6;        // layer 0..2
  const int lane = tid & 63;
  const int jj   = lane & 31;       // unit owned by this lane pair
  const int klo  = (lane & 32) ? 16 : 0;

  const float* whh = (wv == 0) ? w_hh0 : ((wv == 1) ? w_hh1 : w_hh2);
  const float* wih = (wv == 1) ? w_ih1 : w_ih2;
  const float* bih = (wv == 1) ? b_ih1 : b_ih2;
  const float* bhh = (wv == 1) ? b_hh1 : b_hh2;

  v4f whh4[4][4], wih4[4][4];
  float bias4[4];
  #pragma unroll
  for (int tt = 0; tt < 4; tt++){
    const int G = tt*32 + jj;
    const float sc = (tt == 2) ? (-2.f*L2E) : (-L2E);
    #pragma unroll
    for (int q = 0; q < 4; q++)
      whh4[tt][q] = ((const v4f*)(whh + (size_t)G*HID + klo))[q] * sc;
    if (wv > 0){
      #pragma unroll
      for (int q = 0; q < 4; q++)
        wih4[tt][q] = ((const v4f*)(wih + (size_t)G*HID + klo))[q] * sc;
      bias4[tt] = (bih[G] + bhh[G]) * sc * 0.5f;   // halved: counted twice by pairsum
    } else {
      v4f zf = {0.f,0.f,0.f,0.f};
      #pragma unroll
      for (int q = 0; q < 4; q++) wih4[tt][q] = zf;
      bias4[tt] = 0.f;
    }
  }

  ((uint2*)hsb)[tid] = make_uint2(0u, 0u);   // 192*8B = 1536B = all of hsb

  v4f pbuf[4];
  if (wv == 0){
    #pragma unroll
    for (int u = 0; u < 4; u++)
      pbuf[u] = ((const v4f*)pre0)[(size_t)u*32 + jj];
  }
  float c = 0.f;
  __syncthreads();   // one-time full barrier

  for (int G = 0; G < NGRP; ++G){
    const int tb = 4*(G - wv);
    if (tb >= 0 && tb < S_LEN){
      // hoisted cross-layer bf16 reads (written by prev wave last group)
      uint4 crA[4], crB[4];
      if (wv > 0){
        #pragma unroll
        for (int u = 0; u < 4; u++){
          const uint4* hp = (const uint4*)&hsb[wv-1][(tb+u) & 7][klo];
          crA[u] = hp[0]; crB[u] = hp[1];
        }
      }
      #pragma unroll
      for (int u = 0; u < 4; u++){
        const int t = tb + u;

        // cross-layer matvec into xa/xb (independent of own-h round trip)
        v2f xa[4], xb[4];
        #pragma unroll
        for (int tt = 0; tt < 4; tt++){
          xa[tt] = (v2f){bias4[tt], 0.f};   // bias/2, doubled by pairsum
          xb[tt] = (v2f){0.f, 0.f};
        }
        if (wv > 0){
          unsigned ux[8] = {crA[u].x, crA[u].y, crA[u].z, crA[u].w,
                            crB[u].x, crB[u].y, crB[u].z, crB[u].w};
          #pragma unroll
          for (int q = 0; q < 4; q++){
            v2f hl = bf2f2(ux[2*q]);
            v2f hh = bf2f2(ux[2*q + 1]);
            #pragma unroll
            for (int tt = 0; tt < 4; tt++){
              if (q < 2){
                xa[tt] = pkfma(vlo(wih4[tt][q]), hl, xa[tt]);
                xa[tt] = pkfma(vhi(wih4[tt][q]), hh, xa[tt]);
              } else {
                xb[tt] = pkfma(vlo(wih4[tt][q]), hl, xb[tt]);
                xb[tt] = pkfma(vhi(wih4[tt][q]), hh, xb[tt]);
              }
            }
          }
        }

        // own-h matvec (LDS round trip on the chain)
        v2f oa[4], ob[4];
        #pragma unroll
        for (int tt = 0; tt < 4; tt++){
          oa[tt] = (v2f){0.f, 0.f}; ob[tt] = (v2f){0.f, 0.f};
        }
        {
          const uint4* hp = (const uint4*)&hsb[wv][(t-1) & 7][klo];
          uint4 r0 = hp[0], r1 = hp[1];
          unsigned uo[8] = {r0.x, r0.y, r0.z, r0.w, r1.x, r1.y, r1.z, r1.w};
          #pragma unroll
          for (int q = 0; q < 4; q++){
            v2f hl = bf2f2(uo[2*q]);
            v2f hh = bf2f2(uo[2*q + 1]);
            #pragma unroll
            for (int tt = 0; tt < 4; tt++){
              if (q < 2){
                oa[tt] = pkfma(vlo(whh4[tt][q]), hl, oa[tt]);
                oa[tt] = pkfma(vhi(whh4[tt][q]), hh, oa[tt]);
              } else {
                ob[tt] = pkfma(vlo(whh4[tt][q]), hl, ob[tt]);
                ob[tt] = pkfma(vhi(whh4[tt][q]), hh, ob[tt]);
              }
            }
          }
        }

        float base0 = 0.f, base1 = 0.f, base2 = 0.f, base3 = 0.f;
        if (wv == 0){
          v4f pb = pbuf[u];
          base0 = pb.x; base1 = pb.y; base2 = pb.z; base3 = pb.w;
          int tn = t + 4;
          if (tn < S_LEN) pbuf[u] = ((const v4f*)pre0)[(size_t)tn*32 + jj];
        }

        v2f s0 = (oa[0] + ob[0]) + (xa[0] + xb[0]);
        v2f s1 = (oa[1] + ob[1]) + (xa[1] + xb[1]);
        v2f s2 = (oa[2] + ob[2]) + (xa[2] + xb[2]);
        v2f s3 = (oa[3] + ob[3]) + (xa[3] + xb[3]);
        float g_i = pairsum32(s0.x + s0.y) + base0;
        float g_f = pairsum32(s1.x + s1.y) + base1;
        float g_g = pairsum32(s2.x + s2.y) + base2;
        float g_o = pairsum32(s3.x + s3.y) + base3;
        float si = frcp(1.f + fexp2(g_i));
        float sf = frcp(1.f + fexp2(g_f));
        float tg = fmaf(2.f, frcp(1.f + fexp2(g_g)), -1.f);
        float so = frcp(1.f + fexp2(g_o));
        c = fmaf(sf, c, si * tg);
        float tc = fmaf(2.f, frcp(1.f + fexp2(-2.f*L2E * c)), -1.f);
        float h = so * tc;
        if (lane < 32){
          hsb[wv][t & 7][jj] = (unsigned short)f2bf(h);
          if (wv == 2) h2out[(size_t)t*HID + jj] = h;   // fire-and-forget
        }
      }
    }
    wg_barrier();
  }
}

// ---------------------------------------------------------------------------
// Kernel 3: logits + log_softmax head.
// ---------------------------------------------------------------------------
__global__ __launch_bounds__(256) void head_kernel(
    const float* __restrict__ h2, const float* __restrict__ w_pred,
    const float* __restrict__ b_pred, float* __restrict__ out)
{
  int t = blockIdx.x * 256 + threadIdx.x;
  if (t >= S_LEN) return;
  const v4f* hp = (const v4f*)(h2 + (size_t)t * HID);
  float l0 = b_pred[0], l1 = b_pred[1];
  #pragma unroll
  for (int p = 0; p < 8; p++){
    v4f hv = hp[p];
    v4f w0 = *(const v4f*)&w_pred[4*p];
    v4f w1 = *(const v4f*)&w_pred[HID + 4*p];
    l0 += hv.x*w0.x + hv.y*w0.y + hv.z*w0.z + hv.w*w0.w;
    l1 += hv.x*w1.x + hv.y*w1.y + hv.z*w1.z + hv.w*w1.w;
  }
  float m = fmaxf(l0, l1);
  float z = expf(l0 - m) + expf(l1 - m);
  float lg = logf(z);
  out[2*t]     = l0 - m - lg;
  out[2*t + 1] = l1 - m - lg;
}

extern "C" void kernel_launch(void* const* d_in, const int* in_sizes, int n_in,
                              void* d_out, int out_size, void* d_ws, size_t ws_size,
                              hipStream_t stream)
{
  const float* ctxt   = (const float*)d_in[0];
  const float* freq   = (const float*)d_in[1];
  const float* fert   = (const float*)d_in[2];
  const float* wf     = (const float*)d_in[3];
  const float* bf     = (const float*)d_in[4];
  const float* we     = (const float*)d_in[5];
  const float* be     = (const float*)d_in[6];
  const float* w_pred = (const float*)d_in[7];
  const float* b_pred = (const float*)d_in[8];
  const float* w_ih0  = (const float*)d_in[9];
  const float* w_hh0  = (const float*)d_in[10];
  const float* b_ih0  = (const float*)d_in[11];
  const float* b_hh0  = (const float*)d_in[12];
  const float* w_ih1  = (const float*)d_in[13];
  const float* w_hh1  = (const float*)d_in[14];
  const float* b_ih1  = (const float*)d_in[15];
  const float* b_hh1  = (const float*)d_in[16];
  const float* w_ih2  = (const float*)d_in[17];
  const float* w_hh2  = (const float*)d_in[18];
  const float* b_ih2  = (const float*)d_in[19];
  const float* b_hh2  = (const float*)d_in[20];

  float* pre0 = (float*)d_ws;                       // S*128 floats
  float* h2   = pre0 + (size_t)S_LEN * NG;          // S*32 floats
  float* out  = (float*)d_out;

  hipLaunchKernelGGL(pre0_kernel, dim3(S_LEN/128), dim3(256), 0, stream,
                     ctxt, freq, fert, wf, bf, we, be, w_ih0, b_ih0, b_hh0, pre0);
  hipLaunchKernelGGL(scan_kernel, dim3(1), dim3(192), 0, stream,
                     pre0, w_hh0, w_ih1, w_hh1, b_ih1, b_hh1,
                     w_ih2, w_hh2, b_ih2, b_hh2, h2);
  hipLaunchKernelGGL(head_kernel, dim3(S_LEN/256), dim3(256), 0, stream,
                     h2, w_pred, b_pred, out);
}